// Round 8
// baseline (2549.335 us; speedup 1.0000x reference)
//
#include <hip/hip_runtime.h>
#include <hip/hip_bf16.h>
#include <stdint.h>

// ---------------------------------------------------------------------------
// Kiperwasser parser: embed -> BiLSTM(2 layers, H=256, N=512) -> pair scorer.
// Recurrent scan (round 8): 16 blocks (8 per direction) x 1024 threads.
// Each block owns 32 hidden units (128 gate-rows, full K=256); each thread
// owns a QUARTER row = 16 f16 pairs = 4 named uint4 = 16 weight VGPRs.
// Rounds 2-7 proved the allocator spills any >=64-VGPR pinned set regardless
// of waves_per_eu budget (VGPR_Count stuck 52-84; per-step time == spill
// reload BW 256KB/block / ~150GB/s = 1.64us). 16 regs fits inside even the
// stingiest observed allocation. Partial dots reduce via shfl_xor (8 thr/row);
// h exchanged through sentinel-initialized global slots: each block publishes
// its 16 packed words/step, two waves poll the 112 remote words.
// ---------------------------------------------------------------------------

typedef _Float16 f16x2 __attribute__((ext_vector_type(2)));

#define SCOPE_AGENT __HIP_MEMORY_SCOPE_AGENT
constexpr uint32_t SENT = 0x7FFF7FFFu;  // f16 NaN pair: unreachable as packed h

__device__ __forceinline__ float fdot2f(uint32_t w, uint32_t h, float acc) {
#if __has_builtin(__builtin_amdgcn_fdot2)
  return __builtin_amdgcn_fdot2(__builtin_bit_cast(f16x2, w),
                                __builtin_bit_cast(f16x2, h), acc, false);
#else
  f16x2 a = __builtin_bit_cast(f16x2, w);
  f16x2 b = __builtin_bit_cast(f16x2, h);
  return acc + (float)a.x * (float)b.x + (float)a.y * (float)b.y;
#endif
}

__device__ __forceinline__ uint32_t packpair(float x, float y) {
  f16x2 p;
  p.x = (_Float16)x;
  p.y = (_Float16)y;
  return __builtin_bit_cast(uint32_t, p);
}

__device__ __forceinline__ float fsigm(float x) { return 1.f / (1.f + __expf(-x)); }
__device__ __forceinline__ float ftanh(float x) {
  float e = __expf(2.f * x);
  return 1.f - 2.f / (e + 1.f);
}

// ---------------- workspace layout (bytes) ----------------
constexpr size_t ALN(size_t x) { return (x + 1023) & ~(size_t)1023; }
constexpr size_t O_EX    = 0;                       // 4(ld) * 512 * 128 u32 = 1 MB
constexpr size_t SZ_EX   = 4ull * 512 * 128 * 4;
constexpr size_t O_WPK   = ALN(O_EX + SZ_EX);       // 4(ld) * 8b * 4c * 1024t uint4 = 2 MB
constexpr size_t SZ_WPK  = 4ull * 8 * 4 * 1024 * 16;
constexpr size_t O_X0    = ALN(O_WPK + SZ_WPK);     // 512 x 125 f32
constexpr size_t SZ_X0   = 512ull * 125 * 4;
constexpr size_t O_WTIH0 = ALN(O_X0 + SZ_X0);       // 2 x [128][1024]
constexpr size_t SZ_WTIH0 = 2ull * 128 * 1024 * 4;
constexpr size_t O_WTIH1 = ALN(O_WTIH0 + SZ_WTIH0); // 2 x [512][1024]
constexpr size_t SZ_WTIH1 = 2ull * 512 * 1024 * 4;
constexpr size_t O_WTA   = ALN(O_WTIH1 + SZ_WTIH1); // [512][100]
constexpr size_t SZ_WTAB = 512ull * 100 * 4;
constexpr size_t O_WTB   = ALN(O_WTA + SZ_WTAB);    // [512][100]
constexpr size_t O_PRE0  = ALN(O_WTB + SZ_WTAB);    // 2 x [512][1024]
constexpr size_t SZ_PRE  = 2ull * 512 * 1024 * 4;
constexpr size_t O_PRE1  = ALN(O_PRE0 + SZ_PRE);
constexpr size_t O_H0    = ALN(O_PRE1 + SZ_PRE);    // [512][512]
constexpr size_t SZ_H    = 512ull * 512 * 4;
constexpr size_t O_H1    = ALN(O_H0 + SZ_H);
constexpr size_t O_AM    = ALN(O_H1 + SZ_H);        // [512][100]
constexpr size_t O_BT    = ALN(O_AM + SZ_WTAB);     // [100][512]

// ---------------- kernels ----------------

// sentinel-fill the h-exchange slots (4*512*128 = 262144 words)
__global__ void k_init_ex(uint32_t* __restrict__ ex) {
  ex[(size_t)blockIdx.x * 256 + threadIdx.x] = SENT;
}

// embeds: x0[i][0:100] = word_emb[wi[i]], x0[i][100:125] = pos_emb[pi[i]]
__global__ void k_embed(const int* __restrict__ wi, const int* __restrict__ pi,
                        const float* __restrict__ we, const float* __restrict__ pe,
                        float* __restrict__ x0) {
  int i = blockIdx.x, k = threadIdx.x;
  if (k < 100)      x0[i * 125 + k] = we[(size_t)wi[i] * 100 + k];
  else if (k < 125) x0[i * 125 + k] = pe[(size_t)pi[i] * 25 + (k - 100)];
}

// dst[k][m] = src[m][colOff+k] for k<colCnt else 0 ; dst dims [dstRows][srcRows]
__global__ void k_transpose(const float* __restrict__ src, int srcRows, int srcCols,
                            int colOff, int colCnt, int dstRows, float* __restrict__ dst) {
  __shared__ float tile[32][33];
  int k0 = blockIdx.x * 32, m0 = blockIdx.y * 32;
  int tx = threadIdx.x, ty = threadIdx.y;
#pragma unroll
  for (int i = 0; i < 4; i++) {
    int m = m0 + ty + i * 8, k = k0 + tx;
    float v = 0.f;
    if (m < srcRows && k < colCnt) v = src[(size_t)m * srcCols + colOff + k];
    tile[ty + i * 8][tx] = v;
  }
  __syncthreads();
#pragma unroll
  for (int i = 0; i < 4; i++) {
    int k = k0 + ty + i * 8, m = m0 + tx;
    if (k < dstRows && m < srcRows) dst[(size_t)k * srcRows + m] = tile[tx][ty + i * 8];
  }
}

// Whh (4 x [1024][256] f32) -> packed f16 pairs, layout [ld][b(8)][c(4)][t(1024)]
// uint4. Thread t: rl=t>>3 (row-local), kc=t&7 (k-chunk); gate g=rl>>5,
// unit ul=rl&31; global row R = g*256 + b*32 + ul. uint4 c, component i packs
// W[R][kc*32 + c*8 + 2i .. +1].
__global__ void k_packwhh(const float* __restrict__ whh0, const float* __restrict__ whh1,
                          uint32_t* __restrict__ wpk) {
  int ld = blockIdx.x;   // layer*2 + dir
  int b  = blockIdx.y;   // 0..7
  int c  = blockIdx.z;   // 0..3
  int t  = threadIdx.x;  // 0..1023
  const float* W = (ld < 2) ? (whh0 + (size_t)ld * 1024 * 256)
                            : (whh1 + (size_t)(ld - 2) * 1024 * 256);
  int rl = t >> 3, kc = t & 7;
  int g = rl >> 5, ul = rl & 31;
  int R = g * 256 + b * 32 + ul;
  const float* src = W + (size_t)R * 256 + kc * 32 + c * 8;
  uint4 outv;
  outv.x = packpair(src[0], src[1]);
  outv.y = packpair(src[2], src[3]);
  outv.z = packpair(src[4], src[5]);
  outv.w = packpair(src[6], src[7]);
  ((uint4*)wpk)[(size_t)ld * 32768 + (size_t)b * 4096 + (size_t)c * 1024 + t] = outv;
}

// out[gr][col] (or transposed) = sum_k X[xr][k] * WT[k][col] + bias1[col]+bias2[col]
// WT is [Kpad][Nn] with rows >= Kreal zero-filled.
__global__ __launch_bounds__(256) void k_gemm(
    const float* __restrict__ X, const float* __restrict__ WT,
    const float* __restrict__ bias1, const float* __restrict__ bias2,
    float* __restrict__ out, int Mm, int Nn, int Kpad, int Kreal, int ldx,
    int flipX, int outT) {
  __shared__ float XS[32][64];
  int tid = threadIdx.x;
  int cl = tid & 63, rg = tid >> 6;
  int col = blockIdx.y * 64 + cl;
  int colr = (col < Nn) ? col : (Nn - 1);
  int row0 = blockIdx.x * 32;
  float acc[8];
#pragma unroll
  for (int r = 0; r < 8; r++) acc[r] = 0.f;
  for (int k0 = 0; k0 < Kpad; k0 += 64) {
#pragma unroll
    for (int ii = 0; ii < 8; ii++) {
      int idx = ii * 256 + tid;
      int r = idx >> 6, kk = idx & 63;
      int gr = row0 + r;
      int xr = flipX ? (Mm - 1 - gr) : gr;
      int k = k0 + kk;
      XS[r][kk] = (k < Kreal) ? X[(size_t)xr * ldx + k] : 0.f;
    }
    __syncthreads();
#pragma unroll 4
    for (int kk = 0; kk < 64; kk++) {
      float w = WT[(size_t)(k0 + kk) * Nn + colr];
#pragma unroll
      for (int r = 0; r < 8; r++) acc[r] += XS[rg * 8 + r][kk] * w;
    }
    __syncthreads();
  }
  if (col < Nn) {
    float bb = (bias1 ? bias1[col] : 0.f) + (bias2 ? bias2[col] : 0.f);
#pragma unroll
    for (int r = 0; r < 8; r++) {
      int gr = row0 + rg * 8 + r;
      float v = acc[r] + bb;
      if (outT) out[(size_t)col * Mm + gr] = v;
      else      out[(size_t)gr * Nn + col] = v;
    }
  }
}

// Recurrent scan. Grid = 16 blocks: dir d = bx>>3, segment b = bx&7.
// 1024 threads: rl = t>>3 in [0,128) local gate-row, kc = t&7 k-chunk.
// Global row R = (rl>>5)*256 + b*32 + (rl&31); thread covers k in
// [kc*32, kc*32+32) = 4 uint4 weight regs. 8-thread shfl reduce per row.
__global__ __launch_bounds__(1024)
__attribute__((amdgpu_waves_per_eu(4, 4)))
void k_lstm(
    const float* __restrict__ preBase, const uint32_t* __restrict__ wpkL,
    float* __restrict__ hout, uint32_t* __restrict__ exL) {
  int d = blockIdx.x >> 3, b = blockIdx.x & 7;
  int t = threadIdx.x;
  int rl = t >> 3, kc = t & 7;
  const float* pre = preBase + (size_t)d * 512 * 1024;
  uint32_t* ex = exL + (size_t)d * 512 * 128;
  const uint4* wv = ((const uint4*)wpkL) + (size_t)(d * 8 + b) * 4096;

  __shared__ __align__(16) uint32_t h2[128];  // packed f16 pairs of full h[256]
  __shared__ float s1[128];                   // per-row reduced gate pre-acts

  // ---- weight prologue: 4 named uint4 = 16 VGPRs ----
  uint4 W0 = wv[t];
  uint4 W1 = wv[1024 + t];
  uint4 W2 = wv[2048 + t];
  uint4 W3 = wv[3072 + t];
#define WPIN(W) asm volatile("" : "+v"(W.x), "+v"(W.y), "+v"(W.z), "+v"(W.w));
  WPIN(W0) WPIN(W1) WPIN(W2) WPIN(W3)
#undef WPIN

  if (t < 128) h2[t] = 0u;
  float cst = 0.f;  // cell state (lanes t<32 only)
  const int g = rl >> 5, ul = rl & 31;
  const int RR = g * 256 + b * 32 + ul;
  const int kc4 = kc * 4;
  float pcur = (kc == 0) ? pre[RR] : 0.f;
  __syncthreads();

  for (int s = 0; s < 512; s++) {
    float pnext = (kc == 0 && s < 511) ? pre[(size_t)(s + 1) * 1024 + RR] : 0.f;
    // quarter-row dot: 16 dot2 against 4 pinned uint4
    float a0 = pcur, a1 = 0.f, a2 = 0.f, a3 = 0.f;
    const uint4* h4 = (const uint4*)h2;
    {
      uint4 hv = h4[kc4 + 0];
      a0 = fdot2f(W0.x, hv.x, a0); a1 = fdot2f(W0.y, hv.y, a1);
      a2 = fdot2f(W0.z, hv.z, a2); a3 = fdot2f(W0.w, hv.w, a3);
    }
    {
      uint4 hv = h4[kc4 + 1];
      a0 = fdot2f(W1.x, hv.x, a0); a1 = fdot2f(W1.y, hv.y, a1);
      a2 = fdot2f(W1.z, hv.z, a2); a3 = fdot2f(W1.w, hv.w, a3);
    }
    {
      uint4 hv = h4[kc4 + 2];
      a0 = fdot2f(W2.x, hv.x, a0); a1 = fdot2f(W2.y, hv.y, a1);
      a2 = fdot2f(W2.z, hv.z, a2); a3 = fdot2f(W2.w, hv.w, a3);
    }
    {
      uint4 hv = h4[kc4 + 3];
      a0 = fdot2f(W3.x, hv.x, a0); a1 = fdot2f(W3.y, hv.y, a1);
      a2 = fdot2f(W3.z, hv.z, a2); a3 = fdot2f(W3.w, hv.w, a3);
    }
    float p = (a0 + a1) + (a2 + a3);
    // reduce the 8 k-chunks of this row (lanes t..t^7 in-wave)
    p += __shfl_xor(p, 1);
    p += __shfl_xor(p, 2);
    p += __shfl_xor(p, 4);
    if (kc == 0) s1[rl] = p;
    __syncthreads();

    if (t < 32) {
      // gates for unit u=t: s1 rows [i:0-31, f:32-63, g:64-95, o:96-127]
      float gi = s1[t], gf = s1[32 + t], gg = s1[64 + t], go = s1[96 + t];
      cst = fsigm(gf) * cst + fsigm(gi) * ftanh(gg);
      float h = fsigm(go) * ftanh(cst);
      float hB = __shfl_down(h, 1);
      if (!(t & 1)) {  // even lane packs units (t, t+1) -> word b*16 + t/2
        uint32_t pk = packpair(h, hB);
        int j = b * 16 + (t >> 1);
        __hip_atomic_store(&ex[(size_t)s * 128 + j], pk,
                           __ATOMIC_RELAXED, SCOPE_AGENT);
        h2[j] = pk;
      }
      int pos = (d == 0) ? s : (511 - s);
      hout[(size_t)pos * 512 + d * 256 + b * 32 + t] = h;
    } else if (t >= 64 && t < 192) {
      // waves 1-2: poll the 112 remote words (own 16 handled above)
      int j2 = t - 64;
      if ((j2 >> 4) != b) {
        uint32_t q;
        do {
          q = __hip_atomic_load(&ex[(size_t)s * 128 + j2],
                                __ATOMIC_RELAXED, SCOPE_AGENT);
        } while (__any(q == SENT));
        h2[j2] = q;
      }
    }
    pcur = pnext;
    __syncthreads();
  }
}

// scores[i][j] = b2 + sum_m W2[m] * tanh(a[i][m] + bT[m][j])   (b1 folded into a)
__global__ __launch_bounds__(512) void k_score(
    const float* __restrict__ am, const float* __restrict__ bT,
    const float* __restrict__ W2, const float* __restrict__ b2,
    float* __restrict__ out) {
  int i = blockIdx.x;
  int j = threadIdx.x;
  __shared__ float aL[100], w2L[100];
  if (j < 100) { aL[j] = am[(size_t)i * 100 + j]; w2L[j] = W2[j]; }
  __syncthreads();
  float acc = b2[0];
#pragma unroll 4
  for (int m = 0; m < 100; m++)
    acc += w2L[m] * ftanh(aL[m] + bT[(size_t)m * 512 + j]);
  out[(size_t)i * 512 + j] = acc;
}

// ---------------- launch ----------------
extern "C" void kernel_launch(void* const* d_in, const int* in_sizes, int n_in,
                              void* d_out, int out_size, void* d_ws, size_t ws_size,
                              hipStream_t stream) {
  const int*   wi   = (const int*)d_in[0];
  const int*   pi   = (const int*)d_in[1];
  const float* we   = (const float*)d_in[2];
  const float* pe   = (const float*)d_in[3];
  const float* Wih0 = (const float*)d_in[4];
  const float* Whh0 = (const float*)d_in[5];
  const float* bih0 = (const float*)d_in[6];
  const float* bhh0 = (const float*)d_in[7];
  const float* Wih1 = (const float*)d_in[8];
  const float* Whh1 = (const float*)d_in[9];
  const float* bih1 = (const float*)d_in[10];
  const float* bhh1 = (const float*)d_in[11];
  const float* W1   = (const float*)d_in[12];
  const float* b1   = (const float*)d_in[13];
  const float* W2   = (const float*)d_in[14];
  const float* b2   = (const float*)d_in[15];

  char* ws = (char*)d_ws;
  uint32_t* ex    = (uint32_t*)(ws + O_EX);
  uint32_t* wpk   = (uint32_t*)(ws + O_WPK);
  float* x0    = (float*)(ws + O_X0);
  float* wtih0 = (float*)(ws + O_WTIH0);
  float* wtih1 = (float*)(ws + O_WTIH1);
  float* wta   = (float*)(ws + O_WTA);
  float* wtb   = (float*)(ws + O_WTB);
  float* pre0  = (float*)(ws + O_PRE0);
  float* pre1  = (float*)(ws + O_PRE1);
  float* h0    = (float*)(ws + O_H0);
  float* h1    = (float*)(ws + O_H1);
  float* am    = (float*)(ws + O_AM);
  float* bt    = (float*)(ws + O_BT);
  float* out   = (float*)d_out;

  k_init_ex<<<1024, 256, 0, stream>>>(ex);  // 262144 words

  k_embed<<<512, 128, 0, stream>>>(wi, pi, we, pe, x0);

  dim3 tb(32, 8);
  k_transpose<<<dim3(4, 32),  tb, 0, stream>>>(Wih0,              1024, 125, 0,   125, 128, wtih0);
  k_transpose<<<dim3(4, 32),  tb, 0, stream>>>(Wih0 + 1024 * 125, 1024, 125, 0,   125, 128, wtih0 + 128 * 1024);
  k_transpose<<<dim3(16, 32), tb, 0, stream>>>(Wih1,              1024, 512, 0,   512, 512, wtih1);
  k_transpose<<<dim3(16, 32), tb, 0, stream>>>(Wih1 + 1024 * 512, 1024, 512, 0,   512, 512, wtih1 + 512 * 1024);
  k_transpose<<<dim3(16, 4),  tb, 0, stream>>>(W1,                100, 1024, 0,   512, 512, wta);
  k_transpose<<<dim3(16, 4),  tb, 0, stream>>>(W1,                100, 1024, 512, 512, 512, wtb);

  k_packwhh<<<dim3(4, 8, 4), 1024, 0, stream>>>(Whh0, Whh1, wpk);

  for (int d = 0; d < 2; d++)
    k_gemm<<<dim3(16, 16), 256, 0, stream>>>(x0, wtih0 + (size_t)d * 128 * 1024,
        bih0 + d * 1024, bhh0 + d * 1024, pre0 + (size_t)d * 512 * 1024,
        512, 1024, 128, 125, 125, d, 0);

  k_lstm<<<16, 1024, 0, stream>>>(pre0, wpk, h0, ex);

  for (int d = 0; d < 2; d++)
    k_gemm<<<dim3(16, 16), 256, 0, stream>>>(h0, wtih1 + (size_t)d * 512 * 1024,
        bih1 + d * 1024, bhh1 + d * 1024, pre1 + (size_t)d * 512 * 1024,
        512, 1024, 512, 512, 512, d, 0);

  k_lstm<<<16, 1024, 0, stream>>>(pre1, wpk + 2 * 131072, h1, ex + 2ull * 512 * 128);

  k_gemm<<<dim3(16, 2), 256, 0, stream>>>(h1, wta, b1, nullptr, am, 512, 100, 512, 512, 512, 0, 0);
  k_gemm<<<dim3(16, 2), 256, 0, stream>>>(h1, wtb, nullptr, nullptr, bt, 512, 100, 512, 512, 512, 0, 1);

  k_score<<<512, 512, 0, stream>>>(am, bt, W2, b2, out);
}